// Round 3
// baseline (830.307 us; speedup 1.0000x reference)
//
#include <hip/hip_runtime.h>
#include <math.h>

#define B_ 4096
#define F_ 32
#define T_ 100
#define H_ 512
#define C_ 8
#define D_ 256

static __device__ __constant__ float BETA_F = 0.95122942450071400910f; // exp(-0.05) rounded to f32

// LDS-tiled transpose: W1 (H,D) -> W1T (D,H), plus W2 (C,H) -> W2T (H,C).
// Grid: 32 tile-blocks for W1 (4 d-tiles x 8 h-tiles) + 1 block for W2T.
__global__ __launch_bounds__(256)
void snn_prep(const float* __restrict__ W1,
              const float* __restrict__ W2,
              float* __restrict__ ws) {
    float* W1T = ws;                         // D_*H_ floats
    float* W2T = ws + (size_t)D_ * H_;       // H_*C_ floats
    const int bid = blockIdx.x;
    const int tid = threadIdx.x;
    if (bid < 32) {
        __shared__ float tile[64][65];
        const int bd = bid & 3;              // d-tile index (D_/64 = 4)
        const int bh = bid >> 2;             // h-tile index (H_/64 = 8)
        const int tx = tid & 63, ty = tid >> 6;   // ty = 0..3
#pragma unroll
        for (int k = 0; k < 16; ++k) {       // 64 rows, 4 at a time
            const int r = ty + 4 * k;
            tile[r][tx] = W1[(size_t)(bh * 64 + r) * D_ + bd * 64 + tx];
        }
        __syncthreads();
#pragma unroll
        for (int k = 0; k < 16; ++k) {
            const int r = ty + 4 * k;
            W1T[(size_t)(bd * 64 + r) * H_ + bh * 64 + tx] = tile[tx][r];
        }
    } else {
        // W2 (8,512) -> W2T (512,8): read coalesced, scatter-write (16 KB)
        for (int i = tid; i < C_ * H_; i += 256) {
            const int c = i >> 9, h = i & 511;
            W2T[h * C_ + c] = W2[i];
        }
    }
}

// One batch element per 128-thread WG (2 waves). Wave w owns h in [256w, 256w+256),
// 4 h per lane: h = 256*w + 64*i + lane (i=0..3).
__global__ __launch_bounds__(128, 8)
void snn_main(const float* __restrict__ spec,   // (B,F)
              const float* __restrict__ ws,     // W1T | W2T
              const float* __restrict__ noise,  // (B,T,D)
              float* __restrict__ out) {        // (B,C)
    const int b = blockIdx.x;
    const int tid = threadIdx.x;
    const int lane = tid & 63;
    const int w = tid >> 6;

    // word-major LDS (kills t-strided bank conflicts in phase 2)
    __shared__ unsigned long long s1mask[8][T_]; // [h-word][t]
    __shared__ float u_lds[C_][T_];              // [c][t]

    const float* __restrict__ W1T = ws;
    const float* __restrict__ W2T = ws + (size_t)D_ * H_;
    const float* __restrict__ NZb = noise + (size_t)b * T_ * D_;

    // ---- encoder activations for this lane's 4 d's (d = lane + 64*j) ----
    // (both waves compute identical pr/ballots; noise re-read hits L1/L2)
    float pr[4];
#pragma unroll
    for (int j = 0; j < 4; ++j) {
        const int d = lane + 64 * j;
        const int f = d >> 3, n = d & 7;
        const float s = spec[b * F_ + f];
        const float p = (float)((double)n / 7.0);   // matches np.linspace(0,1,8)
        const float diff = s - p;                    // f32, as reference
        const float arg = -32.0f * (diff * diff);    // exact scale (1/(2*TW^2)=32)
        pr[j] = (float)exp((double)arg) * 0.1f;      // correctly-rounded f32 exp
    }

    float m1[4];
#pragma unroll
    for (int i = 0; i < 4; ++i) m1[i] = 0.f;

    // prefetch noise for t=0
    float nz0 = NZb[lane], nz1 = NZb[64 + lane], nz2 = NZb[128 + lane], nz3 = NZb[192 + lane];

    const float* __restrict__ W1Tw = W1T + 256 * w + lane;  // wave's half-row base

    for (int t = 0; t < T_; ++t) {
        // prefetch next timestep's noise (clamped to avoid OOB)
        const int tn = (t + 1 < T_) ? (t + 1) : t;
        const float* np_ = NZb + (size_t)tn * D_;
        const float nn0 = np_[lane], nn1 = np_[64 + lane], nn2 = np_[128 + lane], nn3 = np_[192 + lane];

        // spike masks (wave-uniform), bit k of bmJ <-> d = 64*J + k
        unsigned long long bm0 = __ballot(nz0 < pr[0]);
        unsigned long long bm1 = __ballot(nz1 < pr[1]);
        unsigned long long bm2 = __ballot(nz2 < pr[2]);
        unsigned long long bm3 = __ballot(nz3 < pr[3]);
        nz0 = nn0; nz1 = nn1; nz2 = nn2; nz3 = nn3;

        float z[4];
#pragma unroll
        for (int i = 0; i < 4; ++i) z[i] = 0.f;

        // pop events in ascending d (wave-uniform scalar control)
        auto POP = [&]() -> int {
            if (bm0) { const int k = __builtin_ctzll(bm0); bm0 &= bm0 - 1; return k; }
            if (bm1) { const int k = __builtin_ctzll(bm1); bm1 &= bm1 - 1; return 64 + k; }
            if (bm2) { const int k = __builtin_ctzll(bm2); bm2 &= bm2 - 1; return 128 + k; }
            if (bm3) { const int k = __builtin_ctzll(bm3); bm3 &= bm3 - 1; return 192 + k; }
            return -1;
        };

        // depth-2 event pipeline, no register copies (A/B alternate)
        {
            int d0 = POP();
            if (d0 >= 0) {
                float A[4], B[4];
                {
                    const float* r = W1Tw + (size_t)d0 * H_;
#pragma unroll
                    for (int i = 0; i < 4; ++i) A[i] = r[64 * i];
                }
                for (;;) {
                    int d1 = POP();
                    if (d1 < 0) {
#pragma unroll
                        for (int i = 0; i < 4; ++i) z[i] += A[i];
                        break;
                    }
                    {
                        const float* r = W1Tw + (size_t)d1 * H_;
#pragma unroll
                        for (int i = 0; i < 4; ++i) B[i] = r[64 * i];
                    }
#pragma unroll
                    for (int i = 0; i < 4; ++i) z[i] += A[i];
                    d0 = POP();
                    if (d0 < 0) {
#pragma unroll
                        for (int i = 0; i < 4; ++i) z[i] += B[i];
                        break;
                    }
                    {
                        const float* r = W1Tw + (size_t)d0 * H_;
#pragma unroll
                        for (int i = 0; i < 4; ++i) A[i] = r[64 * i];
                    }
#pragma unroll
                    for (int i = 0; i < 4; ++i) z[i] += B[i];
                }
            }
        }

        // membrane update, threshold, reset; ballot s1 into LDS (word 4w+i)
#pragma unroll
        for (int i = 0; i < 4; ++i) {
            const float mm = __fadd_rn(__fmul_rn(BETA_F, m1[i]), z[i]);
            const bool s = mm > 1.0f;
            const unsigned long long sb = __ballot(s);
            m1[i] = s ? 0.f : mm;
            if (lane == 0) s1mask[4 * w + i][t] = sb;
        }
    }

    __syncthreads();

    // ---- layer 2 drive: u[t][c] = s1[t] @ W2T, one t per thread ----
    if (tid < T_) {
        const int t = tid;
        float u[8];
#pragma unroll
        for (int c = 0; c < 8; ++c) u[c] = 0.f;
#pragma unroll
        for (int j = 0; j < 8; ++j) {              // ascending h
            unsigned long long m = s1mask[j][t];
            while (m) {
                const int k = __builtin_ctzll(m);
                m &= m - 1;
                const int h = 64 * j + k;
                const float4 wlo = ((const float4*)(W2T + h * 8))[0];
                const float4 whi = ((const float4*)(W2T + h * 8))[1];
                u[0] += wlo.x; u[1] += wlo.y; u[2] += wlo.z; u[3] += wlo.w;
                u[4] += whi.x; u[5] += whi.y; u[6] += whi.z; u[7] += whi.w;
            }
        }
#pragma unroll
        for (int c = 0; c < 8; ++c) u_lds[c][t] = u[c];
    }

    __syncthreads();

    // ---- serial m2 scan + spike count ----
    if (tid < 8) {
        float m2 = 0.f, acc = 0.f;
        for (int t = 0; t < T_; ++t) {
            const float uu = u_lds[tid][t];
            float mm = __fadd_rn(__fmul_rn(BETA_F, m2), uu);
            if (mm > 1.0f) { acc += 1.f; mm = 0.f; }
            m2 = mm;
        }
        out[b * C_ + tid] = acc / 100.0f;
    }
}

extern "C" void kernel_launch(void* const* d_in, const int* in_sizes, int n_in,
                              void* d_out, int out_size, void* d_ws, size_t ws_size,
                              hipStream_t stream) {
    const float* spec  = (const float*)d_in[0];  // (4096, 32)
    const float* W1    = (const float*)d_in[1];  // (512, 256)
    const float* W2    = (const float*)d_in[2];  // (8, 512)
    const float* noise = (const float*)d_in[3];  // (4096, 100, 256)
    float* out = (float*)d_out;                  // (4096, 8)
    float* ws  = (float*)d_ws;                   // >= (256*512 + 512*8)*4 bytes

    snn_prep<<<dim3(33), dim3(256), 0, stream>>>(W1, W2, ws);
    snn_main<<<dim3(B_), dim3(128), 0, stream>>>(spec, ws, noise, out);
}